// Round 1
// baseline (1728.848 us; speedup 1.0000x reference)
//
#include <hip/hip_runtime.h>
#include <hip/hip_bf16.h>
#include <math.h>

// HelicalGNNFrontend: 2-layer GATv2 (heads=1, self-loops, mean loop edge_attr)
// N=50000 nodes, E=800000 edges, NODE_DIM=HID=128, EDGE_DIM=32.
//
// Plan:
//  - CSR build by dst (counting sort: hist -> single-block scan -> scatter)
//  - loop_attr[i] = mean of incoming edge_attr (computed once, reused by both layers)
//  - per layer: dual GEMM (xl = h@Wl+bl, xr = h@Wr) -> edge-parallel logits ->
//    node-parallel softmax + aggregate + bo + SiLU (no feature-wide atomics).
// All fp32. Edge-index dtype (int32 vs int64) detected on device.

#define HIP_N 50000
#define HIP_E 800000
#define HIP_H 128
#define HIP_ED 32
#define NEG_SLOPE 0.2f

// ---------------- edge-index dtype detection ----------------
// If the buffer is int64 (values < 2^31, nonneg), every odd int32 word is 0.
// If int32, odd words are real node indices (random in [0,50000)) -> some nonzero.
__global__ void k_detect(const int* __restrict__ ei, int* __restrict__ is32) {
    int j = blockIdx.x * blockDim.x + threadIdx.x;   // j in [0, 4096)
    if (j < 4096) {
        if (ei[2 * j + 1] != 0) atomicOr(is32, 1);
    }
}

__device__ __forceinline__ int fetch_idx(const int* __restrict__ ei, int is32, long long pos) {
    // pos indexes the flattened [2, E] int array (src: pos=e, dst: pos=E+e)
    return is32 ? ei[pos] : ei[2 * pos];  // little-endian low word for int64
}

// ---------------- CSR build ----------------
__global__ void k_hist(const int* __restrict__ ei, const int* __restrict__ flag,
                       int* __restrict__ deg) {
    int is32 = *flag;
    int e = blockIdx.x * blockDim.x + threadIdx.x;
    if (e < HIP_E) {
        int d = fetch_idx(ei, is32, (long long)HIP_E + e);
        atomicAdd(&deg[d], 1);
    }
}

__global__ void k_scan(const int* __restrict__ deg, int* __restrict__ offs,
                       int* __restrict__ cursor, int n) {
    __shared__ int buf[1024];
    __shared__ int carry_sh;
    int t = threadIdx.x;
    if (t == 0) carry_sh = 0;
    __syncthreads();
    for (int base = 0; base < n; base += 1024) {
        int i = base + t;
        int v = (i < n) ? deg[i] : 0;
        buf[t] = v;
        __syncthreads();
        for (int off = 1; off < 1024; off <<= 1) {
            int add = (t >= off) ? buf[t - off] : 0;
            __syncthreads();
            buf[t] += add;
            __syncthreads();
        }
        int incl = buf[t];
        int carry = carry_sh;
        if (i < n) {
            int excl = carry + incl - v;
            offs[i] = excl;
            cursor[i] = excl;
        }
        __syncthreads();
        if (t == 1023) carry_sh = carry + incl;
        __syncthreads();
    }
    if (t == 0) offs[n] = carry_sh;
}

__global__ void k_scatter(const int* __restrict__ ei, const int* __restrict__ flag,
                          int* __restrict__ cursor, int* __restrict__ e_src,
                          int* __restrict__ e_dst, int* __restrict__ e_id) {
    int is32 = *flag;
    int e = blockIdx.x * blockDim.x + threadIdx.x;
    if (e < HIP_E) {
        int s = fetch_idx(ei, is32, e);
        int d = fetch_idx(ei, is32, (long long)HIP_E + e);
        int pos = atomicAdd(&cursor[d], 1);
        e_src[pos] = s;
        e_dst[pos] = d;
        e_id[pos] = e;
    }
}

// loop_attr[i][d] = (sum of edge_attr over incoming edges) / max(deg,1)
__global__ void k_loopattr(const int* __restrict__ offs, const int* __restrict__ e_id,
                           const float* __restrict__ ea, float* __restrict__ loop_attr) {
    int node = blockIdx.x * 4 + (threadIdx.x >> 5);
    int d = threadIdx.x & 31;
    if (node < HIP_N) {
        int o0 = offs[node], o1 = offs[node + 1];
        float acc = 0.f;
        for (int e = o0; e < o1; ++e)
            acc += ea[(size_t)e_id[e] * HIP_ED + d];
        float dg = (float)(o1 - o0);
        loop_attr[(size_t)node * HIP_ED + d] = acc / fmaxf(dg, 1.f);
    }
}

// ---------------- GEMMs (fp32, LDS-tiled, 32 rows/block) ----------------
__global__ __launch_bounds__(256) void k_emb(const float* __restrict__ x,
                                             const float* __restrict__ W,
                                             const float* __restrict__ b,
                                             float* __restrict__ h, int n) {
    __shared__ float tile[32][128];
    int rb = blockIdx.x * 32;
    int tid = threadIdx.x;
    for (int j = 0; j < 16; ++j) {
        int idx = j * 256 + tid;
        int r = idx >> 7, c = idx & 127;
        int row = rb + r;
        tile[r][c] = (row < n) ? x[(size_t)row * 128 + c] : 0.f;
    }
    __syncthreads();
    int c = tid & 127, g = tid >> 7;
    float acc[16];
#pragma unroll
    for (int r = 0; r < 16; ++r) acc[r] = 0.f;
    for (int d4 = 0; d4 < 32; ++d4) {
        int d = d4 * 4;
        float w0 = W[(d + 0) * 128 + c];
        float w1 = W[(d + 1) * 128 + c];
        float w2 = W[(d + 2) * 128 + c];
        float w3 = W[(d + 3) * 128 + c];
#pragma unroll
        for (int r = 0; r < 16; ++r) {
            const float4 hv = *(const float4*)&tile[g * 16 + r][d];
            acc[r] += hv.x * w0 + hv.y * w1 + hv.z * w2 + hv.w * w3;
        }
    }
    float bb = b[c];
    for (int r = 0; r < 16; ++r) {
        int row = rb + g * 16 + r;
        if (row < n) h[(size_t)row * 128 + c] = acc[r] + bb;
    }
}

__global__ __launch_bounds__(256) void k_lin(const float* __restrict__ h,
                                             const float* __restrict__ Wl,
                                             const float* __restrict__ bl,
                                             const float* __restrict__ Wr,
                                             float* __restrict__ xl,
                                             float* __restrict__ xr, int n) {
    __shared__ float tile[32][128];
    int rb = blockIdx.x * 32;
    int tid = threadIdx.x;
    for (int j = 0; j < 16; ++j) {
        int idx = j * 256 + tid;
        int r = idx >> 7, c = idx & 127;
        int row = rb + r;
        tile[r][c] = (row < n) ? h[(size_t)row * 128 + c] : 0.f;
    }
    __syncthreads();
    int c = tid & 127, g = tid >> 7;
    float accl[16], accr[16];
#pragma unroll
    for (int r = 0; r < 16; ++r) { accl[r] = 0.f; accr[r] = 0.f; }
    for (int d4 = 0; d4 < 32; ++d4) {
        int d = d4 * 4;
        float wl0 = Wl[(d + 0) * 128 + c];
        float wl1 = Wl[(d + 1) * 128 + c];
        float wl2 = Wl[(d + 2) * 128 + c];
        float wl3 = Wl[(d + 3) * 128 + c];
        float wr0 = Wr[(d + 0) * 128 + c];
        float wr1 = Wr[(d + 1) * 128 + c];
        float wr2 = Wr[(d + 2) * 128 + c];
        float wr3 = Wr[(d + 3) * 128 + c];
#pragma unroll
        for (int r = 0; r < 16; ++r) {
            const float4 hv = *(const float4*)&tile[g * 16 + r][d];
            accl[r] += hv.x * wl0 + hv.y * wl1 + hv.z * wl2 + hv.w * wl3;
            accr[r] += hv.x * wr0 + hv.y * wr1 + hv.z * wr2 + hv.w * wr3;
        }
    }
    float bb = bl[c];
    for (int r = 0; r < 16; ++r) {
        int row = rb + g * 16 + r;
        if (row < n) {
            xl[(size_t)row * 128 + c] = accl[r] + bb;
            xr[(size_t)row * 128 + c] = accr[r];
        }
    }
}

// ---------------- edge logits (sorted edge list) ----------------
// logit[pos] = leaky_relu(xl[src] + xr[dst] + ea@We) . att
__global__ __launch_bounds__(256) void k_edge_logits(
    const int* __restrict__ e_src, const int* __restrict__ e_dst,
    const int* __restrict__ e_id, const float* __restrict__ ea,
    const float* __restrict__ We, const float* __restrict__ att,
    const float* __restrict__ xl, const float* __restrict__ xr,
    float* __restrict__ logits) {
    __shared__ float ea_sh[2][HIP_ED];
    __shared__ float red[2][2];
    int sub = threadIdx.x >> 7;
    int k = threadIdx.x & 127;
    int pos = blockIdx.x * 2 + sub;
    bool valid = pos < HIP_E;
    int s = 0, dn = 0, eid = 0;
    if (valid) {
        s = e_src[pos];
        dn = e_dst[pos];
        eid = e_id[pos];
        if (k < HIP_ED) ea_sh[sub][k] = ea[(size_t)eid * HIP_ED + k];
    }
    __syncthreads();
    float val = 0.f;
    if (valid) {
        val = xl[(size_t)s * 128 + k] + xr[(size_t)dn * 128 + k];
#pragma unroll
        for (int d = 0; d < HIP_ED; ++d) val += ea_sh[sub][d] * We[d * 128 + k];
        val = val > 0.f ? val : NEG_SLOPE * val;
        val *= att[k];
    }
#pragma unroll
    for (int off = 32; off > 0; off >>= 1) val += __shfl_down(val, off);
    int lane = threadIdx.x & 63;
    int wv = (threadIdx.x >> 6) & 1;
    if (lane == 0) red[sub][wv] = val;
    __syncthreads();
    if (valid && k == 0) logits[pos] = red[sub][0] + red[sub][1];
}

// ---------------- per-node softmax + aggregation + bias + SiLU ----------------
__global__ __launch_bounds__(128) void k_node_finish(
    const int* __restrict__ offs, const int* __restrict__ e_src,
    const float* __restrict__ logits, const float* __restrict__ loop_attr,
    const float* __restrict__ We, const float* __restrict__ att,
    const float* __restrict__ xl, const float* __restrict__ xr,
    const float* __restrict__ bo, float* __restrict__ hout) {
    __shared__ float la_sh[HIP_ED];
    __shared__ float red[2];
    int i = blockIdx.x;
    int k = threadIdx.x;
    int o0 = offs[i], o1 = offs[i + 1];
    if (k < HIP_ED) la_sh[k] = loop_attr[(size_t)i * HIP_ED + k];
    __syncthreads();
    float xli = xl[(size_t)i * 128 + k];
    float msg = xli + xr[(size_t)i * 128 + k];
#pragma unroll
    for (int d = 0; d < HIP_ED; ++d) msg += la_sh[d] * We[d * 128 + k];
    msg = msg > 0.f ? msg : NEG_SLOPE * msg;
    float v = msg * att[k];
#pragma unroll
    for (int off = 32; off > 0; off >>= 1) v += __shfl_down(v, off);
    int lane = k & 63, wv = k >> 6;
    if (lane == 0) red[wv] = v;
    __syncthreads();
    float lgl = red[0] + red[1];  // self-loop logit (uniform across block)

    // segment max over incoming edges + self loop
    float m = lgl;
    for (int e = o0; e < o1; ++e) m = fmaxf(m, logits[e]);

    // aggregate: sum ez * xl[src], denom = sum ez  (self loop included)
    float ezl = __expf(lgl - m);
    float denom = ezl;
    float acc = ezl * xli;
    for (int e = o0; e < o1; ++e) {
        float ez = __expf(logits[e] - m);
        int s = e_src[e];
        acc += ez * xl[(size_t)s * 128 + k];
        denom += ez;
    }
    float o = acc / denom + bo[k];
    // SiLU
    hout[(size_t)i * 128 + k] = o / (1.f + __expf(-o));
}

// ---------------- host launch ----------------
extern "C" void kernel_launch(void* const* d_in, const int* in_sizes, int n_in,
                              void* d_out, int out_size, void* d_ws, size_t ws_size,
                              hipStream_t stream) {
    const float* x      = (const float*)d_in[0];
    const int*   ei     = (const int*)d_in[1];
    const float* ea     = (const float*)d_in[2];
    const float* W_emb  = (const float*)d_in[3];
    const float* b_emb  = (const float*)d_in[4];
    const float* Wl1    = (const float*)d_in[5];
    const float* bl1    = (const float*)d_in[6];
    const float* Wr1    = (const float*)d_in[7];
    const float* We1    = (const float*)d_in[8];
    const float* att1   = (const float*)d_in[9];
    const float* bo1    = (const float*)d_in[10];
    const float* Wl2    = (const float*)d_in[11];
    const float* bl2    = (const float*)d_in[12];
    const float* Wr2    = (const float*)d_in[13];
    const float* We2    = (const float*)d_in[14];
    const float* att2   = (const float*)d_in[15];
    const float* bo2    = (const float*)d_in[16];
    float* out = (float*)d_out;

    // workspace carve (256B aligned)
    char* p = (char*)d_ws;
    auto carve = [&](size_t bytes) {
        void* q = (void*)p;
        p += (bytes + 255) / 256 * 256;
        return q;
    };
    float* h        = (float*)carve((size_t)HIP_N * 128 * 4);
    float* xl       = (float*)carve((size_t)HIP_N * 128 * 4);
    float* xr       = (float*)carve((size_t)HIP_N * 128 * 4);
    float* loopat   = (float*)carve((size_t)HIP_N * HIP_ED * 4);
    float* logits   = (float*)carve((size_t)HIP_E * 4);
    int*   deg      = (int*)carve((size_t)HIP_N * 4);
    int*   offs     = (int*)carve((size_t)(HIP_N + 1) * 4);
    int*   cursor   = (int*)carve((size_t)HIP_N * 4);
    int*   e_src    = (int*)carve((size_t)HIP_E * 4);
    int*   e_dst    = (int*)carve((size_t)HIP_E * 4);
    int*   e_id     = (int*)carve((size_t)HIP_E * 4);
    int*   flag     = (int*)carve(256);

    hipMemsetAsync(deg, 0, (size_t)HIP_N * 4, stream);
    hipMemsetAsync(flag, 0, 4, stream);

    k_detect<<<16, 256, 0, stream>>>(ei, flag);
    k_hist<<<(HIP_E + 255) / 256, 256, 0, stream>>>(ei, flag, deg);
    k_scan<<<1, 1024, 0, stream>>>(deg, offs, cursor, HIP_N);
    k_scatter<<<(HIP_E + 255) / 256, 256, 0, stream>>>(ei, flag, cursor, e_src, e_dst, e_id);
    k_loopattr<<<(HIP_N + 3) / 4, 128, 0, stream>>>(offs, e_id, ea, loopat);

    int gemm_grid = (HIP_N + 31) / 32;
    k_emb<<<gemm_grid, 256, 0, stream>>>(x, W_emb, b_emb, h, HIP_N);

    // ----- layer 1 -----
    k_lin<<<gemm_grid, 256, 0, stream>>>(h, Wl1, bl1, Wr1, xl, xr, HIP_N);
    k_edge_logits<<<(HIP_E + 1) / 2, 256, 0, stream>>>(e_src, e_dst, e_id, ea, We1, att1,
                                                       xl, xr, logits);
    k_node_finish<<<HIP_N, 128, 0, stream>>>(offs, e_src, logits, loopat, We1, att1,
                                             xl, xr, bo1, h);

    // ----- layer 2 -----
    k_lin<<<gemm_grid, 256, 0, stream>>>(h, Wl2, bl2, Wr2, xl, xr, HIP_N);
    k_edge_logits<<<(HIP_E + 1) / 2, 256, 0, stream>>>(e_src, e_dst, e_id, ea, We2, att2,
                                                       xl, xr, logits);
    k_node_finish<<<HIP_N, 128, 0, stream>>>(offs, e_src, logits, loopat, We2, att2,
                                             xl, xr, bo2, out);
}

// Round 2
// 1104.385 us; speedup vs baseline: 1.5654x; 1.5654x over previous
//
#include <hip/hip_runtime.h>
#include <hip/hip_bf16.h>
#include <math.h>

// HelicalGNNFrontend: 2-layer GATv2 (heads=1, self-loops, mean loop edge_attr)
// N=50000 nodes, E=800000 edges, NODE_DIM=HID=128, EDGE_DIM=32.
//
// Round 2: fused per-node online-softmax kernel (one wave per node).
//  - xl[src] gathered exactly ONCE per edge (was twice + logits buffer r/w)
//  - xr[dst] is per-node, held in registers
//  - edge_attr pre-permuted to dst-sorted order (streaming reads, reused 2x)
//  - zero barriers / zero LDS in the hot edge loop (wave-local shfl reduce)

#define HIP_N 50000
#define HIP_E 800000
#define HIP_H 128
#define HIP_ED 32
#define NEG_SLOPE 0.2f

// ---------------- edge-index dtype detection ----------------
__global__ void k_detect(const int* __restrict__ ei, int* __restrict__ is32) {
    int j = blockIdx.x * blockDim.x + threadIdx.x;   // j in [0, 4096)
    if (j < 4096) {
        if (ei[2 * j + 1] != 0) atomicOr(is32, 1);
    }
}

__device__ __forceinline__ int fetch_idx(const int* __restrict__ ei, int is32, long long pos) {
    return is32 ? ei[pos] : ei[2 * pos];  // little-endian low word for int64
}

// ---------------- CSR build ----------------
__global__ void k_hist(const int* __restrict__ ei, const int* __restrict__ flag,
                       int* __restrict__ deg) {
    int is32 = *flag;
    int e = blockIdx.x * blockDim.x + threadIdx.x;
    if (e < HIP_E) {
        int d = fetch_idx(ei, is32, (long long)HIP_E + e);
        atomicAdd(&deg[d], 1);
    }
}

__global__ void k_scan(const int* __restrict__ deg, int* __restrict__ offs,
                       int* __restrict__ cursor, int n) {
    __shared__ int buf[1024];
    __shared__ int carry_sh;
    int t = threadIdx.x;
    if (t == 0) carry_sh = 0;
    __syncthreads();
    for (int base = 0; base < n; base += 1024) {
        int i = base + t;
        int v = (i < n) ? deg[i] : 0;
        buf[t] = v;
        __syncthreads();
        for (int off = 1; off < 1024; off <<= 1) {
            int add = (t >= off) ? buf[t - off] : 0;
            __syncthreads();
            buf[t] += add;
            __syncthreads();
        }
        int incl = buf[t];
        int carry = carry_sh;
        if (i < n) {
            int excl = carry + incl - v;
            offs[i] = excl;
            cursor[i] = excl;
        }
        __syncthreads();
        if (t == 1023) carry_sh = carry + incl;
        __syncthreads();
    }
    if (t == 0) offs[n] = carry_sh;
}

__global__ void k_scatter(const int* __restrict__ ei, const int* __restrict__ flag,
                          int* __restrict__ cursor, int* __restrict__ e_src,
                          int* __restrict__ e_id) {
    int is32 = *flag;
    int e = blockIdx.x * blockDim.x + threadIdx.x;
    if (e < HIP_E) {
        int s = fetch_idx(ei, is32, e);
        int d = fetch_idx(ei, is32, (long long)HIP_E + e);
        int pos = atomicAdd(&cursor[d], 1);
        e_src[pos] = s;
        e_id[pos] = e;
    }
}

// ea_sorted[pos] = ea[e_id[pos]]  (rows of 32 floats = 8 float4)
__global__ void k_permute_ea(const int* __restrict__ e_id, const float* __restrict__ ea,
                             float* __restrict__ ea_s) {
    long long idx = (long long)blockIdx.x * 256 + threadIdx.x;  // over E*8 float4s
    if (idx < (long long)HIP_E * 8) {
        int pos = (int)(idx >> 3), q = (int)(idx & 7);
        ((float4*)ea_s)[(size_t)pos * 8 + q] =
            ((const float4*)ea)[(size_t)e_id[pos] * 8 + q];
    }
}

// loop_attr[i][d] = (sum of incoming edge_attr) / max(deg,1)  (streams ea_sorted)
__global__ void k_loopattr(const int* __restrict__ offs, const float* __restrict__ ea_s,
                           float* __restrict__ loop_attr) {
    int node = blockIdx.x * 4 + (threadIdx.x >> 5);
    int d = threadIdx.x & 31;
    if (node < HIP_N) {
        int o0 = offs[node], o1 = offs[node + 1];
        float acc = 0.f;
        for (int e = o0; e < o1; ++e)
            acc += ea_s[(size_t)e * HIP_ED + d];
        float dg = (float)(o1 - o0);
        loop_attr[(size_t)node * HIP_ED + d] = acc / fmaxf(dg, 1.f);
    }
}

// ---------------- GEMMs (fp32, LDS-tiled, 32 rows/block) ----------------
__global__ __launch_bounds__(256) void k_emb(const float* __restrict__ x,
                                             const float* __restrict__ W,
                                             const float* __restrict__ b,
                                             float* __restrict__ h, int n) {
    __shared__ float tile[32][128];
    int rb = blockIdx.x * 32;
    int tid = threadIdx.x;
    for (int j = 0; j < 16; ++j) {
        int idx = j * 256 + tid;
        int r = idx >> 7, c = idx & 127;
        int row = rb + r;
        tile[r][c] = (row < n) ? x[(size_t)row * 128 + c] : 0.f;
    }
    __syncthreads();
    int c = tid & 127, g = tid >> 7;
    float acc[16];
#pragma unroll
    for (int r = 0; r < 16; ++r) acc[r] = 0.f;
    for (int d4 = 0; d4 < 32; ++d4) {
        int d = d4 * 4;
        float w0 = W[(d + 0) * 128 + c];
        float w1 = W[(d + 1) * 128 + c];
        float w2 = W[(d + 2) * 128 + c];
        float w3 = W[(d + 3) * 128 + c];
#pragma unroll
        for (int r = 0; r < 16; ++r) {
            const float4 hv = *(const float4*)&tile[g * 16 + r][d];
            acc[r] += hv.x * w0 + hv.y * w1 + hv.z * w2 + hv.w * w3;
        }
    }
    float bb = b[c];
    for (int r = 0; r < 16; ++r) {
        int row = rb + g * 16 + r;
        if (row < n) h[(size_t)row * 128 + c] = acc[r] + bb;
    }
}

__global__ __launch_bounds__(256) void k_lin(const float* __restrict__ h,
                                             const float* __restrict__ Wl,
                                             const float* __restrict__ bl,
                                             const float* __restrict__ Wr,
                                             float* __restrict__ xl,
                                             float* __restrict__ xr, int n) {
    __shared__ float tile[32][128];
    int rb = blockIdx.x * 32;
    int tid = threadIdx.x;
    for (int j = 0; j < 16; ++j) {
        int idx = j * 256 + tid;
        int r = idx >> 7, c = idx & 127;
        int row = rb + r;
        tile[r][c] = (row < n) ? h[(size_t)row * 128 + c] : 0.f;
    }
    __syncthreads();
    int c = tid & 127, g = tid >> 7;
    float accl[16], accr[16];
#pragma unroll
    for (int r = 0; r < 16; ++r) { accl[r] = 0.f; accr[r] = 0.f; }
    for (int d4 = 0; d4 < 32; ++d4) {
        int d = d4 * 4;
        float wl0 = Wl[(d + 0) * 128 + c];
        float wl1 = Wl[(d + 1) * 128 + c];
        float wl2 = Wl[(d + 2) * 128 + c];
        float wl3 = Wl[(d + 3) * 128 + c];
        float wr0 = Wr[(d + 0) * 128 + c];
        float wr1 = Wr[(d + 1) * 128 + c];
        float wr2 = Wr[(d + 2) * 128 + c];
        float wr3 = Wr[(d + 3) * 128 + c];
#pragma unroll
        for (int r = 0; r < 16; ++r) {
            const float4 hv = *(const float4*)&tile[g * 16 + r][d];
            accl[r] += hv.x * wl0 + hv.y * wl1 + hv.z * wl2 + hv.w * wl3;
            accr[r] += hv.x * wr0 + hv.y * wr1 + hv.z * wr2 + hv.w * wr3;
        }
    }
    float bb = bl[c];
    for (int r = 0; r < 16; ++r) {
        int row = rb + g * 16 + r;
        if (row < n) {
            xl[(size_t)row * 128 + c] = accl[r] + bb;
            xr[(size_t)row * 128 + c] = accr[r];
        }
    }
}

// ---------------- fused per-node online softmax + aggregation ----------------
// One WAVE per node; thread t owns feature dims (2t, 2t+1) as float2.
// logit_e = leaky_relu(xl[src] + xr[i] + ea_e @ We) . att  -> online max/denom/acc.
__global__ __launch_bounds__(256) void k_node_fused(
    const int* __restrict__ offs, const int* __restrict__ e_src,
    const float* __restrict__ ea_s, const float* __restrict__ loopat,
    const float* __restrict__ We, const float* __restrict__ att,
    const float* __restrict__ xl, const float* __restrict__ xr,
    const float* __restrict__ bo, float* __restrict__ hout) {
    int i = blockIdx.x * 4 + (threadIdx.x >> 6);
    int t = threadIdx.x & 63;
    if (i >= HIP_N) return;

    // We columns (2t, 2t+1) in registers: Wreg[d] = We[d][2t..2t+1]
    const float2* We2 = (const float2*)We;
    float2 Wreg[HIP_ED];
#pragma unroll
    for (int d = 0; d < HIP_ED; ++d) Wreg[d] = We2[d * 64 + t];

    float2 attv = ((const float2*)att)[t];
    float2 bov  = ((const float2*)bo)[t];
    float2 xri  = ((const float2*)(xr + (size_t)i * HIP_H))[t];
    float2 xli  = ((const float2*)(xl + (size_t)i * HIP_H))[t];

    // ---- self-loop logit (eproj from loop_attr) ----
    const float4* la4 = (const float4*)(loopat + (size_t)i * HIP_ED);
    float epx = 0.f, epy = 0.f;
#pragma unroll
    for (int q = 0; q < 8; ++q) {
        float4 la = la4[q];
        epx += la.x * Wreg[q*4+0].x + la.y * Wreg[q*4+1].x
             + la.z * Wreg[q*4+2].x + la.w * Wreg[q*4+3].x;
        epy += la.x * Wreg[q*4+0].y + la.y * Wreg[q*4+1].y
             + la.z * Wreg[q*4+2].y + la.w * Wreg[q*4+3].y;
    }
    float mx = xli.x + xri.x + epx;
    float my = xli.y + xri.y + epy;
    mx = mx > 0.f ? mx : NEG_SLOPE * mx;
    my = my > 0.f ? my : NEG_SLOPE * my;
    float part = mx * attv.x + my * attv.y;
#pragma unroll
    for (int off = 32; off > 0; off >>= 1) part += __shfl_xor(part, off);

    float m = part;        // running max (self-loop logit)
    float denom = 1.f;     // exp(self - self) = 1
    float accx = xli.x, accy = xli.y;

    int o0 = offs[i], o1 = offs[i + 1];
    for (int e = o0; e < o1; ++e) {
        int s = e_src[e];
        float2 xlj = ((const float2*)(xl + (size_t)s * HIP_H))[t];
        const float4* ea4 = (const float4*)(ea_s + (size_t)e * HIP_ED);
        float ex = 0.f, ey = 0.f;
#pragma unroll
        for (int q = 0; q < 8; ++q) {
            float4 ea = ea4[q];
            ex += ea.x * Wreg[q*4+0].x + ea.y * Wreg[q*4+1].x
                + ea.z * Wreg[q*4+2].x + ea.w * Wreg[q*4+3].x;
            ey += ea.x * Wreg[q*4+0].y + ea.y * Wreg[q*4+1].y
                + ea.z * Wreg[q*4+2].y + ea.w * Wreg[q*4+3].y;
        }
        float vx = xlj.x + xri.x + ex;
        float vy = xlj.y + xri.y + ey;
        vx = vx > 0.f ? vx : NEG_SLOPE * vx;
        vy = vy > 0.f ? vy : NEG_SLOPE * vy;
        float p = vx * attv.x + vy * attv.y;
#pragma unroll
        for (int off = 32; off > 0; off >>= 1) p += __shfl_xor(p, off);

        if (p > m) {                      // online rescale
            float sc = __expf(m - p);
            accx *= sc; accy *= sc; denom *= sc;
            m = p;
        }
        float w = __expf(p - m);
        accx += w * xlj.x;
        accy += w * xlj.y;
        denom += w;
    }

    float ox = accx / denom + bov.x;
    float oy = accy / denom + bov.y;
    float2 o;
    o.x = ox / (1.f + __expf(-ox));
    o.y = oy / (1.f + __expf(-oy));
    ((float2*)(hout + (size_t)i * HIP_H))[t] = o;
}

// ---------------- host launch ----------------
extern "C" void kernel_launch(void* const* d_in, const int* in_sizes, int n_in,
                              void* d_out, int out_size, void* d_ws, size_t ws_size,
                              hipStream_t stream) {
    const float* x      = (const float*)d_in[0];
    const int*   ei     = (const int*)d_in[1];
    const float* ea     = (const float*)d_in[2];
    const float* W_emb  = (const float*)d_in[3];
    const float* b_emb  = (const float*)d_in[4];
    const float* Wl1    = (const float*)d_in[5];
    const float* bl1    = (const float*)d_in[6];
    const float* Wr1    = (const float*)d_in[7];
    const float* We1    = (const float*)d_in[8];
    const float* att1   = (const float*)d_in[9];
    const float* bo1    = (const float*)d_in[10];
    const float* Wl2    = (const float*)d_in[11];
    const float* bl2    = (const float*)d_in[12];
    const float* Wr2    = (const float*)d_in[13];
    const float* We2    = (const float*)d_in[14];
    const float* att2   = (const float*)d_in[15];
    const float* bo2    = (const float*)d_in[16];
    float* out = (float*)d_out;

    char* p = (char*)d_ws;
    auto carve = [&](size_t bytes) {
        void* q = (void*)p;
        p += (bytes + 255) / 256 * 256;
        return q;
    };
    float* h        = (float*)carve((size_t)HIP_N * 128 * 4);
    float* xl       = (float*)carve((size_t)HIP_N * 128 * 4);
    float* xr       = (float*)carve((size_t)HIP_N * 128 * 4);
    float* loopat   = (float*)carve((size_t)HIP_N * HIP_ED * 4);
    float* ea_s     = (float*)carve((size_t)HIP_E * HIP_ED * 4);
    int*   deg      = (int*)carve((size_t)HIP_N * 4);
    int*   offs     = (int*)carve((size_t)(HIP_N + 1) * 4);
    int*   cursor   = (int*)carve((size_t)HIP_N * 4);
    int*   e_src    = (int*)carve((size_t)HIP_E * 4);
    int*   e_id     = (int*)carve((size_t)HIP_E * 4);
    int*   flag     = (int*)carve(256);

    hipMemsetAsync(deg, 0, (size_t)HIP_N * 4, stream);
    hipMemsetAsync(flag, 0, 4, stream);

    k_detect<<<16, 256, 0, stream>>>(ei, flag);
    k_hist<<<(HIP_E + 255) / 256, 256, 0, stream>>>(ei, flag, deg);
    k_scan<<<1, 1024, 0, stream>>>(deg, offs, cursor, HIP_N);
    k_scatter<<<(HIP_E + 255) / 256, 256, 0, stream>>>(ei, flag, cursor, e_src, e_id);
    k_permute_ea<<<(HIP_E * 8 + 255) / 256, 256, 0, stream>>>(e_id, ea, ea_s);
    k_loopattr<<<(HIP_N + 3) / 4, 128, 0, stream>>>(offs, ea_s, loopat);

    int gemm_grid = (HIP_N + 31) / 32;
    k_emb<<<gemm_grid, 256, 0, stream>>>(x, W_emb, b_emb, h, HIP_N);

    int fuse_grid = (HIP_N + 3) / 4;
    // ----- layer 1 -----
    k_lin<<<gemm_grid, 256, 0, stream>>>(h, Wl1, bl1, Wr1, xl, xr, HIP_N);
    k_node_fused<<<fuse_grid, 256, 0, stream>>>(offs, e_src, ea_s, loopat, We1, att1,
                                                xl, xr, bo1, h);
    // ----- layer 2 -----
    k_lin<<<gemm_grid, 256, 0, stream>>>(h, Wl2, bl2, Wr2, xl, xr, HIP_N);
    k_node_fused<<<fuse_grid, 256, 0, stream>>>(offs, e_src, ea_s, loopat, We2, att2,
                                                xl, xr, bo2, out);
}